// Round 10
// baseline (2235.853 us; speedup 1.0000x reference)
//
#include <hip/hip_runtime.h>
#include <math.h>

#define Bn 128
#define Tn 256
#define Fn 36
#define Hn 128
#define G4 512
#define BTFn (Bn*Tn*Fn)

// ws float offsets
#define INVD_OFF 0
#define LOSS_OFF 102656
#define IMP_OFF  103040

// ---- LDS word offsets ----
#define OFF_WHH    0       // [kk4<32][e<2][r<512] f16-pairs : 32768
#define OFF_WHIST  32768   // [q<64][f<36]                   : 2304
#define OFF_WF     35072   // [q<18][g<36] diag-zeroed       : 648
#define OFF_WWC    35720   // [q<36][g<36]                   : 1296
#define OFF_IN     37016   // f32 [c<2][w<5][f<36]           : 360
#define OFF_DP     37376   // [c<2][20]                      : 40
#define OFF_MP     37416   // [c<2][20]                      : 40
#define OFF_GXP    37456   // [c<2][20]                      : 40
#define OFF_XCP    37496   // [c<2][20]                      : 40
#define OFF_CCP    37536   // [c<2][20]                      : 40
#define OFF_ALPHA  37576   // f32 [c<2][36]                  : 72
#define OFF_HP     37648   // [c<2][64] f16-pairs            : 128
#define OFF_GFA    37776   // f32 [c<2][512] partial->final  : 1024
#define OFF_GFB    38800   // f32 [c<2][512] partial         : 1024
#define OFF_INVD   39824   // f32 [256]
#define OFF_BH     40080   // 36
#define OFF_BF     40116   // 36
#define OFF_BWC    40152   // 36
#define SMEM_WORDS 40188   // 160752 B <= 160 KiB

typedef _Float16 h2_t __attribute__((ext_vector_type(2)));

__device__ __forceinline__ unsigned int bcu(float x) { return __builtin_bit_cast(unsigned int, x); }
__device__ __forceinline__ unsigned int pkh(float a, float b) {
    return __builtin_bit_cast(unsigned int, __builtin_amdgcn_cvt_pkrtz(a, b));
}
__device__ __forceinline__ float dot2(unsigned int a, unsigned int b, float c) {
    return __builtin_amdgcn_fdot2(__builtin_bit_cast(h2_t, a), __builtin_bit_cast(h2_t, b), c, false);
}
__device__ __forceinline__ float sigmoid_f(float x) {
    return __builtin_amdgcn_rcpf(1.f + __expf(-x));
}
__device__ __forceinline__ float tanh_f(float x) {
    return fmaf(2.f, __builtin_amdgcn_rcpf(1.f + __expf(-2.f * x)), -1.f);
}

// ---------------- prep: inv-denom per t ----------------
__global__ void prep_kernel(const float* __restrict__ data,
                            float* __restrict__ ws) {
    int t = blockIdx.x;
    int tid = threadIdx.x;
    __shared__ float red[256];
    float s = 0.f;
    for (int idx = tid; idx < Bn * Fn; idx += 256) {
        int b = idx / Fn, f = idx - b * Fn;
        s += data[((size_t)(b * 24 + 1) * Tn + t) * Fn + f];
    }
    red[tid] = s;
    __syncthreads();
    for (int off = 128; off > 0; off >>= 1) {
        if (tid < off) red[tid] += red[tid + off];
        __syncthreads();
    }
    if (tid == 0) ws[INVD_OFF + t] = 1.f / (red[0] + 1e-5f);
}

// 18 packed dots from LDS base into acc, fused loads (base must be %4==0)
#define DOT18C(acc, base, woff) do {                                   \
    const unsigned int* _p = &smem[(base)];                            \
    float4 _v0 = *(const float4*)_p;                                   \
    acc = dot2(bcu(_v0.x), wih[(woff) + 0], acc);                      \
    acc = dot2(bcu(_v0.y), wih[(woff) + 1], acc);                      \
    acc = dot2(bcu(_v0.z), wih[(woff) + 2], acc);                      \
    acc = dot2(bcu(_v0.w), wih[(woff) + 3], acc);                      \
    float4 _v1 = *(const float4*)(_p + 4);                             \
    acc = dot2(bcu(_v1.x), wih[(woff) + 4], acc);                      \
    acc = dot2(bcu(_v1.y), wih[(woff) + 5], acc);                      \
    acc = dot2(bcu(_v1.z), wih[(woff) + 6], acc);                      \
    acc = dot2(bcu(_v1.w), wih[(woff) + 7], acc);                      \
    float4 _v2 = *(const float4*)(_p + 8);                             \
    acc = dot2(bcu(_v2.x), wih[(woff) + 8], acc);                      \
    acc = dot2(bcu(_v2.y), wih[(woff) + 9], acc);                      \
    acc = dot2(bcu(_v2.z), wih[(woff) + 10], acc);                     \
    acc = dot2(bcu(_v2.w), wih[(woff) + 11], acc);                     \
    float4 _v3 = *(const float4*)(_p + 12);                            \
    acc = dot2(bcu(_v3.x), wih[(woff) + 12], acc);                     \
    acc = dot2(bcu(_v3.y), wih[(woff) + 13], acc);                     \
    acc = dot2(bcu(_v3.z), wih[(woff) + 14], acc);                     \
    acc = dot2(bcu(_v3.w), wih[(woff) + 15], acc);                     \
    float2 _v4 = *(const float2*)(_p + 16);                            \
    acc = dot2(bcu(_v4.x), wih[(woff) + 16], acc);                     \
    acc = dot2(bcu(_v4.y), wih[(woff) + 17], acc);                     \
} while (0)

// ---------------- main: 512 threads, 2 chains, 3 barriers/step ----------------
__global__ __launch_bounds__(512) void rits_main(
    const float* __restrict__ data,
    const float* __restrict__ W_dh, const float* __restrict__ b_dh,
    const float* __restrict__ W_dx, const float* __restrict__ b_dx,
    const float* __restrict__ W_hist, const float* __restrict__ b_hist,
    const float* __restrict__ W_feat, const float* __restrict__ b_feat,
    const float* __restrict__ W_wc, const float* __restrict__ b_wc,
    const float* __restrict__ W_ih, const float* __restrict__ W_hh,
    const float* __restrict__ b_ih, const float* __restrict__ b_hh,
    const float* __restrict__ W_comb,
    float* __restrict__ ws) {

    extern __shared__ unsigned int smem[];
    float* smf = (float*)smem;

    const int tid = threadIdx.x;
    const int chainA = blockIdx.x * 2, chainB = chainA + 1;
    const int bA = chainA / 3, kA = chainA - 3 * bA;
    const int bB = chainB / 3, kB = chainB - 3 * bB;

    // ---- one-time staging ----
    // WHH: [kk4][e][r] -> conflict-free stride-1 b32 / b128 reads
    for (int i = tid; i < 32768; i += 512) {
        int kk4 = i >> 10, e = (i >> 9) & 1, r = i & 511;
        int k0 = kk4 * 4 + 2 * e;
        float2 wv = *(const float2*)&W_hh[r * Hn + k0];
        smem[OFF_WHH + i] = pkh(wv.x, wv.y);
    }
    for (int i = tid; i < 64 * Fn; i += 512) {
        int q = i / Fn, f = i - q * Fn;
        float2 wv = *(const float2*)&W_hist[f * Hn + 2 * q];
        smem[OFF_WHIST + i] = pkh(wv.x, wv.y);
    }
    for (int i = tid; i < 18 * Fn; i += 512) {
        int q = i / Fn, g = i - q * Fn;
        float2 wv = *(const float2*)&W_feat[g * Fn + 2 * q];
        float w0 = (2 * q     == g) ? 0.f : wv.x;
        float w1 = (2 * q + 1 == g) ? 0.f : wv.y;
        smem[OFF_WF + i] = pkh(w0, w1);
    }
    for (int i = tid; i < 36 * Fn; i += 512) {
        int q = i / Fn, g = i - q * Fn;
        int col = (q < 18) ? 2 * q : Fn + 2 * (q - 18);
        float2 wv = *(const float2*)&W_wc[g * 2 * Fn + col];
        smem[OFF_WWC + i] = pkh(wv.x, wv.y);
    }
    if (tid < Fn) {
        smf[OFF_BH + tid] = b_hist[tid];
        smf[OFF_BF + tid] = b_feat[tid];
        smf[OFF_BWC + tid] = b_wc[tid];
    }
    for (int i = tid; i < Tn; i += 512) smf[OFF_INVD + i] = ws[INVD_OFF + i];
    if (tid < 128) { smem[OFF_HP + tid] = 0; }   // hp = pkh(0,0) for t=0

    // ---- per-row registers ----
    unsigned int wih[36];
    #pragma unroll
    for (int q = 0; q < 36; ++q) {
        float2 wv = *(const float2*)&W_ih[tid * 2 * Fn + 2 * q];
        wih[q] = pkh(wv.x, wv.y);
    }
    const float bias_j = b_ih[tid] + b_hh[tid];
    unsigned int wdh[18];
    float bdh_reg = 0.f;
    {
        int hidx = tid & 127;
        #pragma unroll
        for (int q = 0; q < 18; ++q) {
            float2 wv = *(const float2*)&W_dh[hidx * Fn + 2 * q];
            wdh[q] = pkh(wv.x, wv.y);
        }
        bdh_reg = b_dh[hidx];
    }

    // ---- loader roles (tid>=256): slot1 e=idx (360 total), slot2 e=idx+256 ----
    const float* ldsrc1 = nullptr; int lddst1 = 0, c1 = 0, f1 = 0; bool isd1 = false, ism1 = false;
    const float* ldsrc2 = nullptr; int lddst2 = -1;
    float wdxd_reg = 0.f, bdx_reg = 0.f;
    if (tid >= 256) {
        int idx = tid - 256;
        {
            int e = idx; int c = (e >= 180); int r = e - c * 180;
            int w = r / Fn, f = r - w * Fn;
            int bb = c ? bB : bA, kk = c ? kB : kA;
            int row = (w == 0) ? 1 : (w == 1) ? 2 : (3 + 3 * kk + (w - 2));
            ldsrc1 = data + (size_t)(bb * 24 + row) * Tn * Fn + f;
            lddst1 = OFF_IN + (c * 5 + w) * Fn + f;
            isd1 = (w == 1); ism1 = (w == 0); c1 = c; f1 = f;
            if (isd1) { wdxd_reg = W_dx[f * Fn + f]; bdx_reg = b_dx[f]; }
        }
        if (idx < 104) {
            int e = idx + 256; int r = e - 180;           // always chain B
            int w = r / Fn, f = r - w * Fn;
            int row = 3 + 3 * kB + (w - 2);
            ldsrc2 = data + (size_t)(bB * 24 + row) * Tn * Fn + f;
            lddst2 = OFF_IN + (5 + w) * Fn + f;
        }
    }

    float* impPtr = nullptr;
    if (tid < 128) {
        int c = tid >> 6;
        int mb_ = c ? bB : bA, mk_ = c ? kB : kA;
        impPtr = ws + IMP_OFF + (size_t)(mk_ * Bn + mb_) * Tn * Fn;
    }

    float h_dummy; (void)h_dummy;
    float creg = 0.f, hreg = 0.f, loss_acc = 0.f;
    float gmA = 0.f, gmB = 0.f;
    __syncthreads();

    // ---- prologue: stage t=0 ----
    if (tid >= 256) {
        float v1 = ldsrc1[0];
        smf[lddst1] = v1;
        float v1n = __shfl_xor(v1, 1);
        if (isd1) {
            if (!(f1 & 1)) smem[OFF_DP + c1 * 20 + (f1 >> 1)] = pkh(v1, v1n);
            float gx = __expf(-fmaxf(fmaf(v1, wdxd_reg, bdx_reg), 0.f));
            float gxn = __shfl_xor(gx, 1);
            if (!(f1 & 1)) smem[OFF_GXP + c1 * 20 + (f1 >> 1)] = pkh(gx, gxn);
        }
        if (ism1 && !(f1 & 1)) smem[OFF_MP + c1 * 20 + (f1 >> 1)] = pkh(v1, v1n);
        if (ldsrc2) smf[lddst2] = ldsrc2[0];
    }
    __syncthreads();
    // alpha(0) + gm(0)
    if (tid >= 256) {
        int u = tid - 256;
        if (u < 72) {
            int c = (u >= 36), f = u - 36 * c;
            float a0 = smf[OFF_BWC + f], a1 = 0.f;
            #pragma unroll
            for (int q = 0; q < 18; ++q) {
                a0 = dot2(smem[OFF_GXP + c * 20 + q], smem[OFF_WWC + q * Fn + f], a0);
                a1 = dot2(smem[OFF_MP + c * 20 + q],  smem[OFF_WWC + (18 + q) * Fn + f], a1);
            }
            smf[OFF_ALPHA + c * Fn + f] = a0 + a1;
        }
    }
    DOT18C(gmA, OFF_MP, 18);
    DOT18C(gmB, OFF_MP + 20, 18);
    __syncthreads();

    for (int t = 0; t < Tn; ++t) {
        // ======== P3: features(w0-1) | hh-gates kk4<22 (w4-7) | kk4 22..31 (w2-3) ========
        float pf1v = 0.f, pf2v = 0.f;
        if (tid >= 256) {
            pf1v = ldsrc1[(size_t)(t + 1) * Fn];    // t=255 reads next channel: safe, unused
            if (ldsrc2) pf2v = ldsrc2[(size_t)(t + 1) * Fn];
        }
        if (tid < 128) {
            const int c = tid >> 6, f = tid & 63;
            if (f < Fn) {
                const int inb = OFF_IN + c * 180;
                float m  = smf[inb + f];
                float rt = smf[inb + 72 + f];
                // x_h
                float a0 = smf[OFF_BH + f], a1 = 0.f, a2 = 0.f, a3 = 0.f;
                #pragma unroll
                for (int ch = 0; ch < 8; ++ch) {
                    float4 hL = *(const float4*)&smem[OFF_HP + c * 64 + ch * 8];
                    float4 hH = *(const float4*)&smem[OFF_HP + c * 64 + ch * 8 + 4];
                    a0 = dot2(bcu(hL.x), smem[OFF_WHIST + (ch * 8 + 0) * Fn + f], a0);
                    a1 = dot2(bcu(hL.y), smem[OFF_WHIST + (ch * 8 + 1) * Fn + f], a1);
                    a2 = dot2(bcu(hL.z), smem[OFF_WHIST + (ch * 8 + 2) * Fn + f], a2);
                    a3 = dot2(bcu(hL.w), smem[OFF_WHIST + (ch * 8 + 3) * Fn + f], a3);
                    a0 = dot2(bcu(hH.x), smem[OFF_WHIST + (ch * 8 + 4) * Fn + f], a0);
                    a1 = dot2(bcu(hH.y), smem[OFF_WHIST + (ch * 8 + 5) * Fn + f], a1);
                    a2 = dot2(bcu(hH.z), smem[OFF_WHIST + (ch * 8 + 6) * Fn + f], a2);
                    a3 = dot2(bcu(hH.w), smem[OFF_WHIST + (ch * 8 + 7) * Fn + f], a3);
                }
                float xh = (a0 + a1) + (a2 + a3);
                float xc = m * rt + (1.f - m) * xh;
                float xcn = __shfl_xor(xc, 1);
                if (!(f & 1)) smem[OFF_XCP + c * 20 + (f >> 1)] = pkh(xc, xcn);
                float z0 = smf[OFF_BF + f], z1 = 0.f;
                #pragma unroll
                for (int q = 0; q < 18; q += 2) {
                    z0 = dot2(smem[OFF_XCP + c * 20 + q], smem[OFF_WF + q * Fn + f], z0);
                    z1 = dot2(smem[OFF_XCP + c * 20 + q + 1], smem[OFF_WF + (q + 1) * Fn + f], z1);
                }
                float zh = z0 + z1;
                float al = smf[OFF_ALPHA + c * Fn + f];
                float chv = al * zh + (1.f - al) * xh;
                float cc = m * rt + (1.f - m) * chv;
                loss_acc = fmaf((fabsf(rt - xh) + fabsf(rt - zh) + fabsf(rt - chv)) * m,
                                smf[OFF_INVD + t], loss_acc);
                float tr = smf[inb + 108 + f], se = smf[inb + 144 + f];
                impPtr[t * Fn + f] = cc + se + tr;
                float ccn = __shfl_xor(cc, 1);
                if (!(f & 1)) smem[OFF_CCP + c * 20 + (f >> 1)] = pkh(cc, ccn);
            }
        } else if (tid < 256) {
            // waves 2-3: rows 4u..4u+3, kk4 in [22,32), b128 conflict-free
            const int u = tid - 128;
            float aA0 = 0.f, aA1 = 0.f, aA2 = 0.f, aA3 = 0.f;
            float aB0 = 0.f, aB1 = 0.f, aB2 = 0.f, aB3 = 0.f;
            #pragma unroll
            for (int kk = 22; kk < 32; ++kk) {
                unsigned int ha0 = smem[OFF_HP + 2 * kk];
                unsigned int ha1 = smem[OFF_HP + 2 * kk + 1];
                unsigned int hb0 = smem[OFF_HP + 64 + 2 * kk];
                unsigned int hb1 = smem[OFF_HP + 64 + 2 * kk + 1];
                float4 w0 = *(const float4*)&smem[OFF_WHH + kk * 1024 + 4 * u];        // e=0
                float4 w1 = *(const float4*)&smem[OFF_WHH + kk * 1024 + 512 + 4 * u];  // e=1
                aA0 = dot2(ha0, bcu(w0.x), aA0); aA0 = dot2(ha1, bcu(w1.x), aA0);
                aA1 = dot2(ha0, bcu(w0.y), aA1); aA1 = dot2(ha1, bcu(w1.y), aA1);
                aA2 = dot2(ha0, bcu(w0.z), aA2); aA2 = dot2(ha1, bcu(w1.z), aA2);
                aA3 = dot2(ha0, bcu(w0.w), aA3); aA3 = dot2(ha1, bcu(w1.w), aA3);
                aB0 = dot2(hb0, bcu(w0.x), aB0); aB0 = dot2(hb1, bcu(w1.x), aB0);
                aB1 = dot2(hb0, bcu(w0.y), aB1); aB1 = dot2(hb1, bcu(w1.y), aB1);
                aB2 = dot2(hb0, bcu(w0.z), aB2); aB2 = dot2(hb1, bcu(w1.z), aB2);
                aB3 = dot2(hb0, bcu(w0.w), aB3); aB3 = dot2(hb1, bcu(w1.w), aB3);
            }
            float4 vA; vA.x = aA0; vA.y = aA1; vA.z = aA2; vA.w = aA3;
            float4 vB; vB.x = aB0; vB.y = aB1; vB.z = aB2; vB.w = aB3;
            *(float4*)&smf[OFF_GFB + 4 * u] = vA;
            *(float4*)&smf[OFF_GFB + G4 + 4 * u] = vB;
        } else {
            // waves 4-7: rows r0=tid-256, r1=tid, kk4 in [0,22), stride-1 b32
            const int r0 = tid - 256, r1 = tid;
            float a00 = 0.f, a01 = 0.f, b00 = 0.f, b01 = 0.f;
            float a10 = 0.f, a11 = 0.f, b10 = 0.f, b11 = 0.f;
            #pragma unroll
            for (int kk = 0; kk < 22; ++kk) {
                unsigned int ha0 = smem[OFF_HP + 2 * kk];
                unsigned int ha1 = smem[OFF_HP + 2 * kk + 1];
                unsigned int hb0 = smem[OFF_HP + 64 + 2 * kk];
                unsigned int hb1 = smem[OFF_HP + 64 + 2 * kk + 1];
                unsigned int w00 = smem[OFF_WHH + kk * 1024 + r0];
                unsigned int w01 = smem[OFF_WHH + kk * 1024 + 512 + r0];
                unsigned int w10 = smem[OFF_WHH + kk * 1024 + r1];
                unsigned int w11 = smem[OFF_WHH + kk * 1024 + 512 + r1];
                a00 = dot2(ha0, w00, a00); a01 = dot2(ha1, w01, a01);
                b00 = dot2(hb0, w00, b00); b01 = dot2(hb1, w01, b01);
                a10 = dot2(ha0, w10, a10); a11 = dot2(ha1, w11, a11);
                b10 = dot2(hb0, w10, b10); b11 = dot2(hb1, w11, b11);
            }
            smf[OFF_GFA + r0] = a00 + a01;        smf[OFF_GFA + G4 + r0] = b00 + b01;
            smf[OFF_GFA + r1] = a10 + a11;        smf[OFF_GFA + G4 + r1] = b10 + b11;
        }
        __syncthreads();   // B2

        // ======== P5: gate finalize (all 512 rows) + loader writes for t+1 ========
        {
            float gA = bias_j + gmA + smf[OFF_GFA + tid] + smf[OFF_GFB + tid];
            float gB = bias_j + gmB + smf[OFF_GFA + G4 + tid] + smf[OFF_GFB + G4 + tid];
            DOT18C(gA, OFF_CCP, 0);
            DOT18C(gB, OFF_CCP + 20, 0);
            smf[OFF_GFA + tid] = gA;
            smf[OFF_GFA + G4 + tid] = gB;
        }
        if (tid >= 256) {
            smf[lddst1] = pf1v;
            float vn = __shfl_xor(pf1v, 1);
            if (isd1) {
                if (!(f1 & 1)) smem[OFF_DP + c1 * 20 + (f1 >> 1)] = pkh(pf1v, vn);
                float gx = __expf(-fmaxf(fmaf(pf1v, wdxd_reg, bdx_reg), 0.f));
                float gxn = __shfl_xor(gx, 1);
                if (!(f1 & 1)) smem[OFF_GXP + c1 * 20 + (f1 >> 1)] = pkh(gx, gxn);
            }
            if (ism1 && !(f1 & 1)) smem[OFF_MP + c1 * 20 + (f1 >> 1)] = pkh(pf1v, vn);
            if (ldsrc2) smf[lddst2] = pf2v;
        }
        __syncthreads();   // B3

        // ======== P6: LSTM + fused gamma_h(t+1) (w0-3) | alpha(t+1) (w4-7) | gm(t+1) all ========
        if (tid < 256) {
            const int c = tid >> 7, hidx = tid & 127;
            float ig = smf[OFF_GFA + c * G4 + hidx];
            float fg = smf[OFF_GFA + c * G4 + 128 + hidx];
            float gg = smf[OFF_GFA + c * G4 + 256 + hidx];
            float og = smf[OFF_GFA + c * G4 + 384 + hidx];
            creg = sigmoid_f(fg) * creg + sigmoid_f(ig) * tanh_f(gg);
            float hnew = sigmoid_f(og) * tanh_f(creg);
            // gamma_h(t+1) from dp (holds t+1 since P5)
            float g0 = bdh_reg, g1 = 0.f;
            const int db = OFF_DP + c * 20;
            #pragma unroll
            for (int q = 0; q < 18; q += 2) {
                g0 = dot2(smem[db + q], wdh[q], g0);
                g1 = dot2(smem[db + q + 1], wdh[q + 1], g1);
            }
            hreg = hnew * __expf(-fmaxf(g0 + g1, 0.f));
            float hn = __shfl_xor(hreg, 1);
            if (!(hidx & 1)) smem[OFF_HP + c * 64 + (hidx >> 1)] = pkh(hreg, hn);
        } else {
            int u = tid - 256;
            if (u < 72) {
                int c = (u >= 36), f = u - 36 * c;
                float a0 = smf[OFF_BWC + f], a1 = 0.f;
                #pragma unroll
                for (int q = 0; q < 18; ++q) {
                    a0 = dot2(smem[OFF_GXP + c * 20 + q], smem[OFF_WWC + q * Fn + f], a0);
                    a1 = dot2(smem[OFF_MP + c * 20 + q],  smem[OFF_WWC + (18 + q) * Fn + f], a1);
                }
                smf[OFF_ALPHA + c * Fn + f] = a0 + a1;
            }
        }
        gmA = 0.f; gmB = 0.f;
        DOT18C(gmA, OFF_MP, 18);
        DOT18C(gmB, OFF_MP + 20, 18);
        __syncthreads();   // B1
    }

    // ---- per-block loss partial (fixed order -> deterministic) ----
    if (tid < 128) {
        const int c = tid >> 6, f = tid & 63;
        if (f < Fn) smf[OFF_GFA + c * Fn + f] = loss_acc;
    }
    __syncthreads();
    if (tid == 0) {
        float sA = 0.f, sB = 0.f;
        for (int i = 0; i < Fn; ++i) { sA += smf[OFF_GFA + i]; sB += smf[OFF_GFA + Fn + i]; }
        float w0 = W_comb[0], w1 = W_comb[1], w2 = W_comb[2];
        float mx = fmaxf(w0, fmaxf(w1, w2));
        float e0 = expf(w0 - mx), e1 = expf(w1 - mx), e2 = expf(w2 - mx);
        float inv = 1.f / (e0 + e1 + e2);
        float wkA = ((kA == 0) ? e0 : (kA == 1) ? e1 : e2) * inv;
        float wkB = ((kB == 0) ? e0 : (kB == 1) ? e1 : e2) * inv;
        ws[LOSS_OFF + blockIdx.x] = sA * wkA + sB * wkB;
    }
}

// ---------------- k-reduction of imputations ----------------
__global__ void impute_reduce(const float* __restrict__ ws,
                              const float* __restrict__ W_comb,
                              float* __restrict__ out) {
    int idx = blockIdx.x * 256 + threadIdx.x;
    float w0 = W_comb[0], w1 = W_comb[1], w2 = W_comb[2];
    float mx = fmaxf(w0, fmaxf(w1, w2));
    float e0 = expf(w0 - mx), e1 = expf(w1 - mx), e2 = expf(w2 - mx);
    float inv = 1.f / (e0 + e1 + e2);
    const float* imp = ws + IMP_OFF;
    out[1 + idx] = (e0 * imp[idx] + e1 * imp[BTFn + idx] + e2 * imp[2 * BTFn + idx]) * inv;
}

// ---------------- final loss (192 per-block partials) ----------------
__global__ void loss_final(const float* __restrict__ ws,
                           const float* __restrict__ W_comb,
                           float* __restrict__ out) {
    int tid = threadIdx.x;
    __shared__ float red[256];
    const float* lp = ws + LOSS_OFF;
    red[tid] = (tid < 192) ? lp[tid] : 0.f;
    __syncthreads();
    for (int off = 128; off > 0; off >>= 1) {
        if (tid < off) red[tid] += red[tid + off];
        __syncthreads();
    }
    if (tid == 0) {
        float w0 = W_comb[0], w1 = W_comb[1], w2 = W_comb[2];
        float mx = fmaxf(w0, fmaxf(w1, w2));
        float e0 = expf(w0 - mx), e1 = expf(w1 - mx), e2 = expf(w2 - mx);
        float inv = 1.f / (e0 + e1 + e2);
        float wk0 = e0 * inv, wk1 = e1 * inv, wk2 = e2 * inv;
        float reg = 0.1f * (wk0 * (1.f / 24.f) + wk1 * (1.f / 168.f) + wk2 * (1.f / 720.f));
        out[0] = red[0] + (float)Tn * reg;
    }
}

extern "C" void kernel_launch(void* const* d_in, const int* in_sizes, int n_in,
                              void* d_out, int out_size, void* d_ws, size_t ws_size,
                              hipStream_t stream) {
    const float* data   = (const float*)d_in[0];
    const float* W_dh   = (const float*)d_in[1];
    const float* b_dh   = (const float*)d_in[2];
    const float* W_dx   = (const float*)d_in[3];
    const float* b_dx   = (const float*)d_in[4];
    const float* W_hist = (const float*)d_in[5];
    const float* b_hist = (const float*)d_in[6];
    const float* W_feat = (const float*)d_in[7];
    const float* b_feat = (const float*)d_in[8];
    const float* W_wc   = (const float*)d_in[9];
    const float* b_wc   = (const float*)d_in[10];
    const float* W_ih   = (const float*)d_in[11];
    const float* W_hh   = (const float*)d_in[12];
    const float* b_ih   = (const float*)d_in[13];
    const float* b_hh   = (const float*)d_in[14];
    const float* W_comb = (const float*)d_in[15];
    float* ws = (float*)d_ws;
    float* out = (float*)d_out;

    hipLaunchKernelGGL(prep_kernel, dim3(Tn), dim3(256), 0, stream, data, ws);
    hipLaunchKernelGGL(rits_main, dim3(Bn * 3 / 2), dim3(512), SMEM_WORDS * 4, stream,
                       data, W_dh, b_dh, W_dx, b_dx, W_hist, b_hist,
                       W_feat, b_feat, W_wc, b_wc, W_ih, W_hh, b_ih, b_hh, W_comb, ws);
    hipLaunchKernelGGL(impute_reduce, dim3(BTFn / 256), dim3(256), 0, stream, ws, W_comb, out);
    hipLaunchKernelGGL(loss_final, dim3(1), dim3(256), 0, stream, ws, W_comb, out);
}

// Round 11
// 1721.198 us; speedup vs baseline: 1.2990x; 1.2990x over previous
//
#include <hip/hip_runtime.h>
#include <math.h>

#define Bn 128
#define Tn 256
#define Fn 36
#define Hn 128
#define G4 512
#define BTFn (Bn*Tn*Fn)
#define TF 9216

// ws float offsets
#define INVD_OFF 0
#define LOSS_OFF 102656
#define IMP_OFF  103040

// ---- LDS word offsets ----
#define OFF_WHH    0       // [kk4<32][e<2][r<512] f16-pairs : 32768
#define OFF_WHIST  32768   // [q<64][f<36]                   : 2304
#define OFF_WF     35072   // [q<18][g<36] diag-zeroed       : 648
#define OFF_WWC    35720   // [q<36][g<36]                   : 1296
#define OFF_IN     37016   // f32 [c<2][w<5][f<36]           : 360
#define OFF_DP     37376   // [c<2][20]                      : 40
#define OFF_MP     37416   // [par<2][c<2][20]               : 80
#define OFF_GXP    37496   // [c<2][20]                      : 40
#define OFF_XCP    37536   // [c<2][20]                      : 40
#define OFF_CCP    37576   // [c<2][20]                      : 40
#define OFF_ALPHA  37616   // f32 [c<2][36]                  : 72
#define OFF_HP     37688   // [c<2][64] f16-pairs            : 128
#define OFF_GFA    37816   // f32 [c<2][512]                 : 1024
#define OFF_GFB    38840   // f32 [c<2][512]                 : 1024
#define OFF_INVD   39864   // f32 [256]
#define OFF_BH     40120   // 36
#define OFF_BF     40156   // 36
#define OFF_BWC    40192   // 36
#define SMEM_WORDS 40228   // 160912 B

typedef _Float16 h2_t __attribute__((ext_vector_type(2)));

__device__ __forceinline__ unsigned int bcu(float x) { return __builtin_bit_cast(unsigned int, x); }
__device__ __forceinline__ unsigned int pkh(float a, float b) {
    return __builtin_bit_cast(unsigned int, __builtin_amdgcn_cvt_pkrtz(a, b));
}
__device__ __forceinline__ float dot2(unsigned int a, unsigned int b, float c) {
    return __builtin_amdgcn_fdot2(__builtin_bit_cast(h2_t, a), __builtin_bit_cast(h2_t, b), c, false);
}
__device__ __forceinline__ float sigmoid_f(float x) {
    return __builtin_amdgcn_rcpf(1.f + __expf(-x));
}
__device__ __forceinline__ float tanh_f(float x) {
    return fmaf(2.f, __builtin_amdgcn_rcpf(1.f + __expf(-2.f * x)), -1.f);
}

// ---------------- prep: inv-denom per t ----------------
__global__ void prep_kernel(const float* __restrict__ data,
                            float* __restrict__ ws) {
    int t = blockIdx.x;
    int tid = threadIdx.x;
    __shared__ float red[256];
    float s = 0.f;
    for (int idx = tid; idx < Bn * Fn; idx += 256) {
        int b = idx / Fn, f = idx - b * Fn;
        s += data[((size_t)(b * 24 + 1) * Tn + t) * Fn + f];
    }
    red[tid] = s;
    __syncthreads();
    for (int off = 128; off > 0; off >>= 1) {
        if (tid < off) red[tid] += red[tid + off];
        __syncthreads();
    }
    if (tid == 0) ws[INVD_OFF + t] = 1.f / (red[0] + 1e-5f);
}

// 18 packed dots from LDS base (must be %4==0) against wih[woff..woff+17]
#define DOT18M(acc, base, woff) do {                                   \
    const unsigned int* _p = &smem[(base)];                            \
    float _a = 0.f, _b = 0.f;                                          \
    float4 _v0 = *(const float4*)_p;                                   \
    _a = dot2(bcu(_v0.x), wih[(woff) + 0], _a);                        \
    _b = dot2(bcu(_v0.y), wih[(woff) + 1], _b);                        \
    _a = dot2(bcu(_v0.z), wih[(woff) + 2], _a);                        \
    _b = dot2(bcu(_v0.w), wih[(woff) + 3], _b);                        \
    float4 _v1 = *(const float4*)(_p + 4);                             \
    _a = dot2(bcu(_v1.x), wih[(woff) + 4], _a);                        \
    _b = dot2(bcu(_v1.y), wih[(woff) + 5], _b);                        \
    _a = dot2(bcu(_v1.z), wih[(woff) + 6], _a);                        \
    _b = dot2(bcu(_v1.w), wih[(woff) + 7], _b);                        \
    float4 _v2 = *(const float4*)(_p + 8);                             \
    _a = dot2(bcu(_v2.x), wih[(woff) + 8], _a);                        \
    _b = dot2(bcu(_v2.y), wih[(woff) + 9], _b);                        \
    _a = dot2(bcu(_v2.z), wih[(woff) + 10], _a);                       \
    _b = dot2(bcu(_v2.w), wih[(woff) + 11], _b);                       \
    float4 _v3 = *(const float4*)(_p + 12);                            \
    _a = dot2(bcu(_v3.x), wih[(woff) + 12], _a);                       \
    _b = dot2(bcu(_v3.y), wih[(woff) + 13], _b);                       \
    _a = dot2(bcu(_v3.z), wih[(woff) + 14], _a);                       \
    _b = dot2(bcu(_v3.w), wih[(woff) + 15], _b);                       \
    float2 _v4 = *(const float2*)(_p + 16);                            \
    _a = dot2(bcu(_v4.x), wih[(woff) + 16], _a);                       \
    _b = dot2(bcu(_v4.y), wih[(woff) + 17], _b);                       \
    acc += _a + _b;                                                    \
} while (0)

// loader staging of one float2 into LDS (P = MP parity)
#define STAGE(v, P) do {                                                          \
    if (lw == 0) {                                                                \
        *(float2*)&smf[OFF_IN + lc * 180 + 2 * lu] = (v);                         \
        smem[OFF_MP + (P) * 40 + lc * 20 + lu] = pkh((v).x, (v).y);               \
    } else if (lw == 1) {                                                         \
        smem[OFF_DP + lc * 20 + lu] = pkh((v).x, (v).y);                          \
        float _g0 = __expf(-fmaxf(fmaf((v).x, wdxd0, bdx0), 0.f));                \
        float _g1 = __expf(-fmaxf(fmaf((v).y, wdxd1, bdx1), 0.f));                \
        smem[OFF_GXP + lc * 20 + lu] = pkh(_g0, _g1);                             \
    } else {                                                                      \
        *(float2*)&smf[OFF_IN + lc * 180 + lw * 36 + 2 * lu] = (v);               \
    }                                                                             \
} while (0)

// ---------------- main: 512 threads, 2 chains, 3 barriers/step ----------------
__global__ __launch_bounds__(512) void rits_main(
    const float* __restrict__ data,
    const float* __restrict__ W_dh, const float* __restrict__ b_dh,
    const float* __restrict__ W_dx, const float* __restrict__ b_dx,
    const float* __restrict__ W_hist, const float* __restrict__ b_hist,
    const float* __restrict__ W_feat, const float* __restrict__ b_feat,
    const float* __restrict__ W_wc, const float* __restrict__ b_wc,
    const float* __restrict__ W_ih, const float* __restrict__ W_hh,
    const float* __restrict__ b_ih, const float* __restrict__ b_hh,
    const float* __restrict__ W_comb,
    float* __restrict__ ws) {

    extern __shared__ unsigned int smem[];
    float* smf = (float*)smem;

    const int tid = threadIdx.x;
    const int chainA = blockIdx.x * 2, chainB = chainA + 1;
    const int bA = chainA / 3, kA = chainA - 3 * bA;
    const int bB = chainB / 3, kB = chainB - 3 * bB;

    // ---- one-time staging ----
    for (int i = tid; i < 32768; i += 512) {
        int kk4 = i >> 10, e = (i >> 9) & 1, r = i & 511;
        float2 wv = *(const float2*)&W_hh[r * Hn + kk4 * 4 + 2 * e];
        smem[OFF_WHH + i] = pkh(wv.x, wv.y);
    }
    for (int i = tid; i < 64 * Fn; i += 512) {
        int q = i / Fn, f = i - q * Fn;
        float2 wv = *(const float2*)&W_hist[f * Hn + 2 * q];
        smem[OFF_WHIST + i] = pkh(wv.x, wv.y);
    }
    for (int i = tid; i < 18 * Fn; i += 512) {
        int q = i / Fn, g = i - q * Fn;
        float2 wv = *(const float2*)&W_feat[g * Fn + 2 * q];
        float w0 = (2 * q     == g) ? 0.f : wv.x;
        float w1 = (2 * q + 1 == g) ? 0.f : wv.y;
        smem[OFF_WF + i] = pkh(w0, w1);
    }
    for (int i = tid; i < 36 * Fn; i += 512) {
        int q = i / Fn, g = i - q * Fn;
        int col = (q < 18) ? 2 * q : Fn + 2 * (q - 18);
        float2 wv = *(const float2*)&W_wc[g * 2 * Fn + col];
        smem[OFF_WWC + i] = pkh(wv.x, wv.y);
    }
    if (tid < Fn) {
        smf[OFF_BH + tid] = b_hist[tid];
        smf[OFF_BF + tid] = b_feat[tid];
        smf[OFF_BWC + tid] = b_wc[tid];
    }
    for (int i = tid; i < Tn; i += 512) smf[OFF_INVD + i] = ws[INVD_OFF + i];
    if (tid < 128) smem[OFF_HP + tid] = 0;

    // ---- per-row registers ----
    unsigned int wih[36];
    #pragma unroll
    for (int q = 0; q < 36; ++q) {
        float2 wv = *(const float2*)&W_ih[tid * 2 * Fn + 2 * q];
        wih[q] = pkh(wv.x, wv.y);
    }
    const float bias_j = b_ih[tid] + b_hh[tid];
    unsigned int wdh[18];
    float bdh_reg = 0.f;
    {
        int hidx = tid & 127;
        #pragma unroll
        for (int q = 0; q < 18; ++q) {
            float2 wv = *(const float2*)&W_dh[hidx * Fn + 2 * q];
            wdh[q] = pkh(wv.x, wv.y);
        }
        bdh_reg = b_dh[hidx];
    }

    // ---- feature role (waves 0-1, lanes 0-17) ----
    const int fc = tid >> 6, fu = tid & 63;
    const bool isfeat = (tid < 128) && (fu < 18);
    float* impp = nullptr;
    if (isfeat) {
        int b_ = fc ? bB : bA, k_ = fc ? kB : kA;
        impp = ws + IMP_OFF + (size_t)(k_ * Bn + b_) * TF;
    }

    // ---- loader role (tid in [256, 436)) ----
    const float* ldsrc = nullptr; int lw = 0, lc = 0, lu = 0;
    float wdxd0 = 0.f, wdxd1 = 0.f, bdx0 = 0.f, bdx1 = 0.f;
    if (tid >= 256 && tid < 436) {
        int idx = tid - 256;
        lc = idx / 90; int r = idx - 90 * lc;
        lw = r / 18; lu = r - 18 * lw;
        int bb = lc ? bB : bA, kk = lc ? kB : kA;
        int row = (lw == 0) ? 1 : (lw == 1) ? 2 : (3 + 3 * kk + (lw - 2));
        ldsrc = data + (size_t)(bb * 24 + row) * TF + 2 * lu;
        if (lw == 1) {
            wdxd0 = W_dx[(2 * lu) * Fn + 2 * lu]; wdxd1 = W_dx[(2 * lu + 1) * Fn + 2 * lu + 1];
            bdx0 = b_dx[2 * lu]; bdx1 = b_dx[2 * lu + 1];
        }
    }

    float creg = 0.f, hreg = 0.f, loss_acc = 0.f;
    __syncthreads();

    // ---- prologue: load inputs 0..3, stage t=0 (MP parity 0) ----
    float2 cur0 = {0,0}, cur1 = {0,0}, cur2 = {0,0}, cur3 = {0,0};
    float2 nxt0 = {0,0}, nxt1 = {0,0}, nxt2 = {0,0}, nxt3 = {0,0};
    if (ldsrc) {
        cur0 = *(const float2*)(ldsrc);
        cur1 = *(const float2*)(ldsrc + Fn);
        cur2 = *(const float2*)(ldsrc + 2 * Fn);
        cur3 = *(const float2*)(ldsrc + 3 * Fn);
        STAGE(cur0, 0);
    }
    __syncthreads();
    // alpha(0)
    if (tid >= 256) {
        int u = tid - 256;
        if (u < 72) {
            int c = (u >= 36), f = u - 36 * c;
            float a0 = smf[OFF_BWC + f], a1 = 0.f;
            #pragma unroll
            for (int q = 0; q < 18; ++q) {
                a0 = dot2(smem[OFF_GXP + c * 20 + q], smem[OFF_WWC + q * Fn + f], a0);
                a1 = dot2(smem[OFF_MP + c * 20 + q],  smem[OFF_WWC + (18 + q) * Fn + f], a1);
            }
            smf[OFF_ALPHA + c * Fn + f] = a0 + a1;
        }
    }
    __syncthreads();

    for (int t8 = 0; t8 < Tn; t8 += 4) {
        float2 iv0 = {0,0}, iv1 = {0,0}, iv2 = {0,0}, iv3 = {0,0};
        #pragma unroll
        for (int s = 0; s < 4; ++s) {
            const int t = t8 + s;
            const int par = t & 1, parn = par ^ 1;

            // ======== P3: features (w0-1) | hh kk22-31 b128 (w2-3) | hh kk0-21 (w4-7) ========
            if (tid < 128) {
                if (fu < 18) {
                    const int inb = OFF_IN + fc * 180;
                    float2 mv = *(const float2*)&smf[inb + 2 * fu];
                    float2 rv = *(const float2*)&smf[inb + 72 + 2 * fu];
                    float a0 = 0.f, a1 = 0.f, a2 = 0.f, a3 = 0.f;
                    float b0 = 0.f, b1 = 0.f, b2 = 0.f, b3 = 0.f;
                    #pragma unroll
                    for (int q = 0; q < 64; q += 4) {
                        unsigned int h0 = smem[OFF_HP + fc * 64 + q];
                        unsigned int h1 = smem[OFF_HP + fc * 64 + q + 1];
                        unsigned int h2 = smem[OFF_HP + fc * 64 + q + 2];
                        unsigned int h3 = smem[OFF_HP + fc * 64 + q + 3];
                        float2 w0 = *(const float2*)&smem[OFF_WHIST + q * Fn + 2 * fu];
                        float2 w1 = *(const float2*)&smem[OFF_WHIST + (q + 1) * Fn + 2 * fu];
                        float2 w2 = *(const float2*)&smem[OFF_WHIST + (q + 2) * Fn + 2 * fu];
                        float2 w3 = *(const float2*)&smem[OFF_WHIST + (q + 3) * Fn + 2 * fu];
                        a0 = dot2(h0, bcu(w0.x), a0); b0 = dot2(h0, bcu(w0.y), b0);
                        a1 = dot2(h1, bcu(w1.x), a1); b1 = dot2(h1, bcu(w1.y), b1);
                        a2 = dot2(h2, bcu(w2.x), a2); b2 = dot2(h2, bcu(w2.y), b2);
                        a3 = dot2(h3, bcu(w3.x), a3); b3 = dot2(h3, bcu(w3.y), b3);
                    }
                    float2 bh = *(const float2*)&smf[OFF_BH + 2 * fu];
                    float xh0 = (a0 + a1) + (a2 + a3) + bh.x;
                    float xh1 = (b0 + b1) + (b2 + b3) + bh.y;
                    float xc0 = mv.x * rv.x + (1.f - mv.x) * xh0;
                    float xc1 = mv.y * rv.y + (1.f - mv.y) * xh1;
                    smem[OFF_XCP + fc * 20 + fu] = pkh(xc0, xc1);
                    // zh: same-wave LDS round-trip (no barrier needed)
                    float z0 = 0.f, z1 = 0.f, y0 = 0.f, y1 = 0.f;
                    #pragma unroll
                    for (int q = 0; q < 18; q += 2) {
                        unsigned int x0 = smem[OFF_XCP + fc * 20 + q];
                        unsigned int x1 = smem[OFF_XCP + fc * 20 + q + 1];
                        float2 wf0 = *(const float2*)&smem[OFF_WF + q * Fn + 2 * fu];
                        float2 wf1 = *(const float2*)&smem[OFF_WF + (q + 1) * Fn + 2 * fu];
                        z0 = dot2(x0, bcu(wf0.x), z0); y0 = dot2(x0, bcu(wf0.y), y0);
                        z1 = dot2(x1, bcu(wf1.x), z1); y1 = dot2(x1, bcu(wf1.y), y1);
                    }
                    float2 bf = *(const float2*)&smf[OFF_BF + 2 * fu];
                    float zh0 = z0 + z1 + bf.x, zh1 = y0 + y1 + bf.y;
                    float2 av = *(const float2*)&smf[OFF_ALPHA + fc * Fn + 2 * fu];
                    float ch0 = av.x * zh0 + (1.f - av.x) * xh0;
                    float ch1 = av.y * zh1 + (1.f - av.y) * xh1;
                    float cc0 = mv.x * rv.x + (1.f - mv.x) * ch0;
                    float cc1 = mv.y * rv.y + (1.f - mv.y) * ch1;
                    float invt = smf[OFF_INVD + t];
                    loss_acc += ((fabsf(rv.x - xh0) + fabsf(rv.x - zh0) + fabsf(rv.x - ch0)) * mv.x
                               + (fabsf(rv.y - xh1) + fabsf(rv.y - zh1) + fabsf(rv.y - ch1)) * mv.y) * invt;
                    smem[OFF_CCP + fc * 20 + fu] = pkh(cc0, cc1);
                    float2 tv = *(const float2*)&smf[inb + 108 + 2 * fu];
                    float2 sv = *(const float2*)&smf[inb + 144 + 2 * fu];
                    float2 iv; iv.x = cc0 + sv.x + tv.x; iv.y = cc1 + sv.y + tv.y;
                    if (s == 0) iv0 = iv; else if (s == 1) iv1 = iv;
                    else if (s == 2) iv2 = iv; else iv3 = iv;
                }
            } else if (tid < 256) {
                const int u = tid - 128;      // rows 4u..4u+3, kk 22..31 (b128)
                float aA0 = 0.f, aA1 = 0.f, aA2 = 0.f, aA3 = 0.f;
                float aB0 = 0.f, aB1 = 0.f, aB2 = 0.f, aB3 = 0.f;
                #pragma unroll
                for (int kk = 22; kk < 32; ++kk) {
                    unsigned int ha0 = smem[OFF_HP + 2 * kk];
                    unsigned int ha1 = smem[OFF_HP + 2 * kk + 1];
                    unsigned int hb0 = smem[OFF_HP + 64 + 2 * kk];
                    unsigned int hb1 = smem[OFF_HP + 64 + 2 * kk + 1];
                    float4 w0 = *(const float4*)&smem[OFF_WHH + kk * 1024 + 4 * u];
                    float4 w1 = *(const float4*)&smem[OFF_WHH + kk * 1024 + 512 + 4 * u];
                    aA0 = dot2(ha0, bcu(w0.x), aA0); aA0 = dot2(ha1, bcu(w1.x), aA0);
                    aA1 = dot2(ha0, bcu(w0.y), aA1); aA1 = dot2(ha1, bcu(w1.y), aA1);
                    aA2 = dot2(ha0, bcu(w0.z), aA2); aA2 = dot2(ha1, bcu(w1.z), aA2);
                    aA3 = dot2(ha0, bcu(w0.w), aA3); aA3 = dot2(ha1, bcu(w1.w), aA3);
                    aB0 = dot2(hb0, bcu(w0.x), aB0); aB0 = dot2(hb1, bcu(w1.x), aB0);
                    aB1 = dot2(hb0, bcu(w0.y), aB1); aB1 = dot2(hb1, bcu(w1.y), aB1);
                    aB2 = dot2(hb0, bcu(w0.z), aB2); aB2 = dot2(hb1, bcu(w1.z), aB2);
                    aB3 = dot2(hb0, bcu(w0.w), aB3); aB3 = dot2(hb1, bcu(w1.w), aB3);
                }
                float4 vA; vA.x = aA0; vA.y = aA1; vA.z = aA2; vA.w = aA3;
                float4 vB; vB.x = aB0; vB.y = aB1; vB.z = aB2; vB.w = aB3;
                *(float4*)&smf[OFF_GFB + 4 * u] = vA;
                *(float4*)&smf[OFF_GFB + G4 + 4 * u] = vB;
            } else {
                if (s == 0 && ldsrc) {   // refill next 4 inputs (once per 4 steps)
                    nxt0 = *(const float2*)(ldsrc + (size_t)(t8 + 4) * Fn);
                    nxt1 = *(const float2*)(ldsrc + (size_t)(t8 + 5) * Fn);
                    nxt2 = *(const float2*)(ldsrc + (size_t)(t8 + 6) * Fn);
                    nxt3 = *(const float2*)(ldsrc + (size_t)(t8 + 7) * Fn);
                }
                const int r0 = tid - 256, r1 = tid;   // kk 0..21, stride-1 b32
                float a00 = 0.f, a01 = 0.f, c00 = 0.f, c01 = 0.f;
                float a10 = 0.f, a11 = 0.f, c10 = 0.f, c11 = 0.f;
                #pragma unroll
                for (int kk = 0; kk < 22; ++kk) {
                    unsigned int ha0 = smem[OFF_HP + 2 * kk];
                    unsigned int ha1 = smem[OFF_HP + 2 * kk + 1];
                    unsigned int hb0 = smem[OFF_HP + 64 + 2 * kk];
                    unsigned int hb1 = smem[OFF_HP + 64 + 2 * kk + 1];
                    unsigned int w00 = smem[OFF_WHH + kk * 1024 + r0];
                    unsigned int w01 = smem[OFF_WHH + kk * 1024 + 512 + r0];
                    unsigned int w10 = smem[OFF_WHH + kk * 1024 + r1];
                    unsigned int w11 = smem[OFF_WHH + kk * 1024 + 512 + r1];
                    a00 = dot2(ha0, w00, a00); a01 = dot2(ha1, w01, a01);
                    c00 = dot2(hb0, w00, c00); c01 = dot2(hb1, w01, c01);
                    a10 = dot2(ha0, w10, a10); a11 = dot2(ha1, w11, a11);
                    c10 = dot2(hb0, w10, c10); c11 = dot2(hb1, w11, c11);
                }
                smf[OFF_GFA + r0] = a00 + a01;       smf[OFF_GFA + G4 + r0] = c00 + c01;
                smf[OFF_GFA + r1] = a10 + a11;       smf[OFF_GFA + G4 + r1] = c10 + c11;
            }
            __syncthreads();   // B2

            // ======== P5: gate finalize (all) + stage inputs(t+1) ========
            {
                float gA = smf[OFF_GFA + tid] + smf[OFF_GFB + tid] + bias_j;
                float gB = smf[OFF_GFA + G4 + tid] + smf[OFF_GFB + G4 + tid] + bias_j;
                DOT18M(gA, OFF_CCP, 0);
                DOT18M(gB, OFF_CCP + 20, 0);
                DOT18M(gA, OFF_MP + par * 40, 18);
                DOT18M(gB, OFF_MP + par * 40 + 20, 18);
                smf[OFF_GFA + tid] = gA;
                smf[OFF_GFA + G4 + tid] = gB;
            }
            if (ldsrc) {
                if (s == 0) STAGE(cur1, parn);
                else if (s == 1) STAGE(cur2, parn);
                else if (s == 2) STAGE(cur3, parn);
                else STAGE(nxt0, parn);
            }
            __syncthreads();   // B3

            // ======== P6: LSTM + decay(t+1) + h-pack (w0-3) | alpha(t+1) (w4-7) ========
            if (tid < 256) {
                const int c = tid >> 7, hidx = tid & 127;
                float ig = smf[OFF_GFA + c * G4 + hidx];
                float fg = smf[OFF_GFA + c * G4 + 128 + hidx];
                float gg = smf[OFF_GFA + c * G4 + 256 + hidx];
                float og = smf[OFF_GFA + c * G4 + 384 + hidx];
                creg = sigmoid_f(fg) * creg + sigmoid_f(ig) * tanh_f(gg);
                float hn_ = sigmoid_f(og) * tanh_f(creg);
                float g0 = bdh_reg, g1 = 0.f;
                #pragma unroll
                for (int q = 0; q < 18; q += 2) {
                    g0 = dot2(smem[OFF_DP + c * 20 + q], wdh[q], g0);
                    g1 = dot2(smem[OFF_DP + c * 20 + q + 1], wdh[q + 1], g1);
                }
                hreg = hn_ * __expf(-fmaxf(g0 + g1, 0.f));
                float hn2 = __shfl_xor(hreg, 1);
                if (!(hidx & 1)) smem[OFF_HP + c * 64 + (hidx >> 1)] = pkh(hreg, hn2);
            } else {
                int u = tid - 256;
                if (u < 72) {
                    int c = (u >= 36), f = u - 36 * c;
                    float a0 = smf[OFF_BWC + f], a1 = 0.f;
                    #pragma unroll
                    for (int q = 0; q < 18; ++q) {
                        a0 = dot2(smem[OFF_GXP + c * 20 + q], smem[OFF_WWC + q * Fn + f], a0);
                        a1 = dot2(smem[OFF_MP + parn * 40 + c * 20 + q], smem[OFF_WWC + (18 + q) * Fn + f], a1);
                    }
                    smf[OFF_ALPHA + c * Fn + f] = a0 + a1;
                }
            }
            __syncthreads();   // B1

            // imp flush every 4 steps (stores drain across next phase)
            if (s == 3 && isfeat) {
                *(float2*)(impp + (size_t)t8 * Fn + 2 * fu)       = iv0;
                *(float2*)(impp + (size_t)(t8 + 1) * Fn + 2 * fu) = iv1;
                *(float2*)(impp + (size_t)(t8 + 2) * Fn + 2 * fu) = iv2;
                *(float2*)(impp + (size_t)(t8 + 3) * Fn + 2 * fu) = iv3;
            }
        }
        if (ldsrc) { cur0 = nxt0; cur1 = nxt1; cur2 = nxt2; cur3 = nxt3; }
    }

    // ---- per-block loss partial (fixed order -> deterministic) ----
    __syncthreads();
    if (isfeat) smf[OFF_GFA + fc * 18 + fu] = loss_acc;
    __syncthreads();
    if (tid == 0) {
        float sA = 0.f, sB = 0.f;
        for (int i = 0; i < 18; ++i) { sA += smf[OFF_GFA + i]; sB += smf[OFF_GFA + 18 + i]; }
        float w0 = W_comb[0], w1 = W_comb[1], w2 = W_comb[2];
        float mx = fmaxf(w0, fmaxf(w1, w2));
        float e0 = expf(w0 - mx), e1 = expf(w1 - mx), e2 = expf(w2 - mx);
        float inv = 1.f / (e0 + e1 + e2);
        float wkA = ((kA == 0) ? e0 : (kA == 1) ? e1 : e2) * inv;
        float wkB = ((kB == 0) ? e0 : (kB == 1) ? e1 : e2) * inv;
        ws[LOSS_OFF + blockIdx.x] = sA * wkA + sB * wkB;
    }
}

// ---------------- k-reduction of imputations ----------------
__global__ void impute_reduce(const float* __restrict__ ws,
                              const float* __restrict__ W_comb,
                              float* __restrict__ out) {
    int idx = blockIdx.x * 256 + threadIdx.x;
    float w0 = W_comb[0], w1 = W_comb[1], w2 = W_comb[2];
    float mx = fmaxf(w0, fmaxf(w1, w2));
    float e0 = expf(w0 - mx), e1 = expf(w1 - mx), e2 = expf(w2 - mx);
    float inv = 1.f / (e0 + e1 + e2);
    const float* imp = ws + IMP_OFF;
    out[1 + idx] = (e0 * imp[idx] + e1 * imp[BTFn + idx] + e2 * imp[2 * BTFn + idx]) * inv;
}

// ---------------- final loss (192 per-block partials) ----------------
__global__ void loss_final(const float* __restrict__ ws,
                           const float* __restrict__ W_comb,
                           float* __restrict__ out) {
    int tid = threadIdx.x;
    __shared__ float red[256];
    const float* lp = ws + LOSS_OFF;
    red[tid] = (tid < 192) ? lp[tid] : 0.f;
    __syncthreads();
    for (int off = 128; off > 0; off >>= 1) {
        if (tid < off) red[tid] += red[tid + off];
        __syncthreads();
    }
    if (tid == 0) {
        float w0 = W_comb[0], w1 = W_comb[1], w2 = W_comb[2];
        float mx = fmaxf(w0, fmaxf(w1, w2));
        float e0 = expf(w0 - mx), e1 = expf(w1 - mx), e2 = expf(w2 - mx);
        float inv = 1.f / (e0 + e1 + e2);
        float wk0 = e0 * inv, wk1 = e1 * inv, wk2 = e2 * inv;
        float reg = 0.1f * (wk0 * (1.f / 24.f) + wk1 * (1.f / 168.f) + wk2 * (1.f / 720.f));
        out[0] = red[0] + (float)Tn * reg;
    }
}

extern "C" void kernel_launch(void* const* d_in, const int* in_sizes, int n_in,
                              void* d_out, int out_size, void* d_ws, size_t ws_size,
                              hipStream_t stream) {
    const float* data   = (const float*)d_in[0];
    const float* W_dh   = (const float*)d_in[1];
    const float* b_dh   = (const float*)d_in[2];
    const float* W_dx   = (const float*)d_in[3];
    const float* b_dx   = (const float*)d_in[4];
    const float* W_hist = (const float*)d_in[5];
    const float* b_hist = (const float*)d_in[6];
    const float* W_feat = (const float*)d_in[7];
    const float* b_feat = (const float*)d_in[8];
    const float* W_wc   = (const float*)d_in[9];
    const float* b_wc   = (const float*)d_in[10];
    const float* W_ih   = (const float*)d_in[11];
    const float* W_hh   = (const float*)d_in[12];
    const float* b_ih   = (const float*)d_in[13];
    const float* b_hh   = (const float*)d_in[14];
    const float* W_comb = (const float*)d_in[15];
    float* ws = (float*)d_ws;
    float* out = (float*)d_out;

    hipLaunchKernelGGL(prep_kernel, dim3(Tn), dim3(256), 0, stream, data, ws);
    hipLaunchKernelGGL(rits_main, dim3(Bn * 3 / 2), dim3(512), SMEM_WORDS * 4, stream,
                       data, W_dh, b_dh, W_dx, b_dx, W_hist, b_hist,
                       W_feat, b_feat, W_wc, b_wc, W_ih, W_hh, b_ih, b_hh, W_comb, ws);
    hipLaunchKernelGGL(impute_reduce, dim3(BTFn / 256), dim3(256), 0, stream, ws, W_comb, out);
    hipLaunchKernelGGL(loss_final, dim3(1), dim3(256), 0, stream, ws, W_comb, out);
}